// Round 10
// baseline (213.420 us; speedup 1.0000x reference)
//
#include <hip/hip_runtime.h>
#include <hip/hip_bf16.h>
#include <math.h>

// MPDO contraction, delta-decomposed bf16 MFMA, kraus-split across 2 waves/element.
// Per site: E' = 2E + c0 + c1,  c_k = a_k^T E + E b_k + a_k^T(E b_k),  a,b = mid - I.
// r9: was latency-bound at 2 waves/SIMD (Occ 19.6%, VALUBusy 51% CU-proxy, MfmaUtil 21%).
// Split k across 2 waves -> 4096 waves, 4/SIMD. Each wave: 6 MFMAs (acc depth 4).
// Contribs exchanged bf16 via LDS; E' finalized kraus-ordered from bf16-rounded contribs
// on BOTH waves -> bitwise-identical fp32 E, no divergence across the pair.
//
// Frag layouts (verified r9 pass): A/B input elem e of lane l <-> k = 8*(l>>5)+e;
// C/D col = lane&31, row = (r&3)+8*(r>>2)+4*(lane>>5)  [m74/m101].

typedef __attribute__((ext_vector_type(8)))  short short8;   // 8 bf16 = 4 VGPR
typedef __attribute__((ext_vector_type(16))) float f32x16;   // MFMA C/D

#define EPITCH 33   // (row*33+col)%32 and (col*33+c)%32 are permutations -> <=2-way (free)

static __device__ inline unsigned pk2(float lo, float hi) {
    union { __hip_bfloat162 h; unsigned u; } cv;
    cv.h = __float22bfloat162_rn(make_float2(lo, hi));       // v_cvt_pk_bf16_f32
    return cv.u;
}
static __device__ inline short8 mk8(unsigned u0, unsigned u1, unsigned u2, unsigned u3) {
    union { short8 v; unsigned u[4]; } r;
    r.u[0] = u0; r.u[1] = u1; r.u[2] = u2; r.u[3] = u3;
    return r.v;
}
static __device__ inline void pl32swap(unsigned& x, unsigned& y) {
    asm("v_permlane32_swap_b32 %0, %1" : "+v"(x), "+v"(y));
}
static __device__ inline f32x16 MFMA(short8 a, short8 b, f32x16 c) {
    return __builtin_amdgcn_mfma_f32_32x32x16_bf16(a, b, c, 0, 0, 0);
}
static __device__ inline f32x16 zero16() {
    f32x16 z = {0.f,0.f,0.f,0.f,0.f,0.f,0.f,0.f,0.f,0.f,0.f,0.f,0.f,0.f,0.f,0.f};
    return z;
}

__global__ __launch_bounds__(256, 4) void mpdo_mfma2(
    const int*   __restrict__ qn,
    const float* __restrict__ left,
    const float* __restrict__ right,
    const float* __restrict__ middle,
    float*       __restrict__ out,
    const int    cplx)
{
    __shared__ unsigned mid_b[2048];           // 8 KB, site tensor bf16 (both s, both k)
    __shared__ float    E_s[2][32*EPITCH];     // 8.4 KB, per-ELEM transposed-E buffer
    __shared__ unsigned cbuf[4][512];          // 8 KB, per-wave bf16 contrib (rp*32+col)

    const int t    = threadIdx.x;
    const int w    = t >> 6;       // 0..3
    const int lane = t & 63;
    const int hi   = lane >> 5;
    const int col  = lane & 31;
    const int ew   = w >> 1;       // elem within block (0..1)
    const int kw   = w & 1;        // kraus index owned by this wave
    const int elem = blockIdx.x * 2 + ew;
    const int* q   = qn + (size_t)elem * 128;
    float* Ew = E_s[ew];

    // staging decomposition (unchanged from r7): 256 threads cover both s slices
    const int sp = (t >> 4) & 15;
    const int sj = t & 15;
    const int jj = sj * 2;
    const float dj = (sp == sj) ? 1.0f : 0.0f;
    const int v0 = (0 + 2*sp) * 16 + sj;
    const int v1 = (32 + 2*sp) * 16 + sj;

    int rowr[16];
    #pragma unroll
    for (int r = 0; r < 16; ++r) rowr[r] = (r & 3) + 8*(r >> 2) + 4*hi;
    // contrib row-pair index for packed reg-pair r (rows rowr[2r], rowr[2r]+1)
    int rpidx[8];
    #pragma unroll
    for (int r = 0; r < 8; ++r) rpidx[r] = (r & 1) + 2*hi + 4*(r >> 1);

    // ---- init edge (fp32 C-layout regs, identical on both waves of the elem) ----
    float e[16];
    {
        const float* Lr = left + (size_t)q[0]  * 64;
        const float* Lc = left + (size_t)q[64] * 64;
        const float c0v = Lc[col*2 + 0], c1v = Lc[col*2 + 1];
        #pragma unroll
        for (int r = 0; r < 16; ++r)
            e[r] = Lr[rowr[r]*2 + 0] * c0v + Lr[rowr[r]*2 + 1] * c1v;
    }

    // ---- prefetch site 1 ----
    const float4* gm = (const float4*)middle;
    float4 A0 = gm[v0], A1 = gm[v0 + 16], B0 = gm[v1], B1 = gm[v1 + 16];
    int srn = q[1], scn = q[65];

    for (int site = 1; site <= 62; ++site) {
        // -- stage mid_b (identity-subtracted bf16 pairs) --
        {
            uint2* m2 = (uint2*)mid_b;
            m2[((0*16 + sp)*32 + jj) >> 1] = make_uint2(pk2(A0.x - dj, A1.x), pk2(A0.z, A1.z - dj));
            m2[((1*16 + sp)*32 + jj) >> 1] = make_uint2(pk2(A0.y - dj, A1.y), pk2(A0.w, A1.w - dj));
            m2[((2*16 + sp)*32 + jj) >> 1] = make_uint2(pk2(B0.x - dj, B1.x), pk2(B0.z, B1.z - dj));
            m2[((3*16 + sp)*32 + jj) >> 1] = make_uint2(pk2(B0.y - dj, B1.y), pk2(B0.w, B1.w - dj));
        }
        // -- Ew write: both waves of the elem write IDENTICAL e (benign duplicate) --
        #pragma unroll
        for (int r = 0; r < 16; ++r) Ew[rowr[r]*EPITCH + col] = e[r];
        __syncthreads();                       // B1: mid_b + Ew ready

        const int sr = srn, sc = scn;
        if (site < 62) {
            const float4* gn = (const float4*)(middle + (size_t)site * 4096);
            A0 = gn[v0]; A1 = gn[v0 + 16]; B0 = gn[v1]; B1 = gn[v1 + 16];
            srn = q[site + 1]; scn = q[site + 65];
        }

        // -- own-kraus fragments only --
        short8 aT[2], bF[2];
        #pragma unroll
        for (int h = 0; h < 2; ++h) {
            const int pa = ((sr*2 + kw)*16 + 8*h + 4*hi) * 32 + col;
            aT[h] = mk8(mid_b[pa], mid_b[pa+32], mid_b[pa+64], mid_b[pa+96]);
            const int pb = ((sc*2 + kw)*16 + 8*h + 4*hi) * 32 + col;
            bF[h] = mk8(mid_b[pb], mid_b[pb+32], mid_b[pb+64], mid_b[pb+96]);
        }
        // -- E as A-operand (transposed via Ew) --
        short8 EA[2];
        #pragma unroll
        for (int h = 0; h < 2; ++h) {
            const int base = col*EPITCH + 16*h + 8*hi;
            const float f0 = Ew[base+0], f1 = Ew[base+1], f2 = Ew[base+2], f3 = Ew[base+3];
            const float f4 = Ew[base+4], f5 = Ew[base+5], f6 = Ew[base+6], f7 = Ew[base+7];
            EA[h] = mk8(pk2(f0,f1), pk2(f2,f3), pk2(f4,f5), pk2(f6,f7));
        }
        // -- E as B-operand (from regs via permlane) --
        short8 EB[2];
        #pragma unroll
        for (int h = 0; h < 2; ++h) {
            unsigned ua = pk2(e[8*h+0], e[8*h+1]);
            unsigned ub = pk2(e[8*h+2], e[8*h+3]);
            unsigned uc = pk2(e[8*h+4], e[8*h+5]);
            unsigned ud = pk2(e[8*h+6], e[8*h+7]);
            pl32swap(ua, uc); pl32swap(ub, ud);
            EB[h] = mk8(ua, ub, uc, ud);
        }

        // -- V = E b_kw ; acc = a_kw^T E + a_kw^T V --
        f32x16 V = MFMA(EA[0], bF[0], zero16());
        V = MFMA(EA[1], bF[1], V);
        f32x16 acc = MFMA(aT[0], EB[0], zero16());
        acc = MFMA(aT[1], EB[1], acc);
        {
            #pragma unroll
            for (int h = 0; h < 2; ++h) {
                unsigned ua = pk2(V[8*h+0], V[8*h+1]);
                unsigned ub = pk2(V[8*h+2], V[8*h+3]);
                unsigned uc = pk2(V[8*h+4], V[8*h+5]);
                unsigned ud = pk2(V[8*h+6], V[8*h+7]);
                pl32swap(ua, uc); pl32swap(ub, ud);
                acc = MFMA(aT[h], mk8(ua, ub, uc, ud), acc);
            }
        }

        // -- contrib c = acc + V, bf16-packed; write to own cbuf --
        unsigned cp[8];
        #pragma unroll
        for (int r = 0; r < 8; ++r) {
            cp[r] = pk2(acc[2*r] + V[2*r], acc[2*r+1] + V[2*r+1]);
            cbuf[w][rpidx[r]*32 + col] = cp[r];
        }
        __syncthreads();                       // B2: contribs ready

        // -- finalize E' = 2E + c_k0 + c_k1 (kraus-ordered, both bf16-rounded) --
        {
            const unsigned* pbuf = &cbuf[w ^ 1][0];
            #pragma unroll
            for (int r = 0; r < 8; ++r) {
                const unsigned uo = cp[r];
                const unsigned up = pbuf[rpidx[r]*32 + col];
                const float o0 = __uint_as_float(uo << 16);
                const float o1 = __uint_as_float(uo & 0xffff0000u);
                const float p0 = __uint_as_float(up << 16);
                const float p1 = __uint_as_float(up & 0xffff0000u);
                if (kw == 0) {
                    e[2*r]   = fmaf(2.f, e[2*r],   o0) + p0;
                    e[2*r+1] = fmaf(2.f, e[2*r+1], o1) + p1;
                } else {
                    e[2*r]   = fmaf(2.f, e[2*r],   p0) + o0;
                    e[2*r+1] = fmaf(2.f, e[2*r+1], p1) + o1;
                }
            }
        }
        // loop-top staging overwrite of mid_b/Ew/cbuf is safe: all reads of the old
        // site precede B2; next writes happen after B1 of the next iteration.
    }

    // ---- epilogue (identical e on both waves; kw==0 writes) ----
    {
        const float* Rr = right + (size_t)q[63]  * 64;
        const float* Rc = right + (size_t)q[127] * 64;
        const float rc0 = Rc[col*2 + 0], rc1 = Rc[col*2 + 1];
        float part = 0.f;
        #pragma unroll
        for (int r = 0; r < 16; ++r) {
            const float re = Rr[rowr[r]*2 + 0]*rc0 + Rr[rowr[r]*2 + 1]*rc1;
            part += e[r] * re;
        }
        #pragma unroll
        for (int off = 32; off > 0; off >>= 1)
            part += __shfl_down(part, off, 64);
        if (lane == 0 && kw == 0) {
            const float re = logf(fabsf(part));
            if (cplx) {
                out[2*elem + 0] = re;
                out[2*elem + 1] = (part < 0.f) ? 3.14159265358979323846f : 0.f;
            } else {
                out[elem] = re;
            }
        }
    }
}

extern "C" void kernel_launch(void* const* d_in, const int* in_sizes, int n_in,
                              void* d_out, int out_size, void* d_ws, size_t ws_size,
                              hipStream_t stream) {
    const int*   qn     = (const int*)  d_in[0];
    const float* left   = (const float*)d_in[1];
    const float* right  = (const float*)d_in[2];
    const float* middle = (const float*)d_in[3];
    float* out = (float*)d_out;

    const int B    = in_sizes[0] / 128;        // qn is [B, 2L], 2L = 128
    const int cplx = (out_size >= 2 * B) ? 1 : 0;
    mpdo_mfma2<<<B / 2, 256, 0, stream>>>(qn, left, right, middle, out, cplx);
}

// Round 11
// 129.247 us; speedup vs baseline: 1.6513x; 1.6513x over previous
//
#include <hip/hip_runtime.h>
#include <hip/hip_bf16.h>
#include <math.h>

// MPDO contraction, delta-decomposed bf16 MFMA, r11 structure:
//  - prestage kernel: middle -> d_ws as delta-subtracted bf16 fragments (frag = 1 dwordx4)
//  - main kernel: 1 wave per element, NO barriers, NO shared staging; per-wave LDS only
//    for the E-transpose round trip; ping-pong fragment prefetch from d_ws (L2).
// r10 lesson: kraus-split duplicated all non-MFMA work -> issue-bound (VALU 70%). This
// version minimizes per-site issue work instead of adding waves.
// Numerics identical to r9 (passed, absmax 0.25): E' = 2E + sum_k[a^T E + E b + a^T(E b)].

typedef __attribute__((ext_vector_type(8)))  short short8;
typedef __attribute__((ext_vector_type(16))) float f32x16;

#define EPITCH 33

static __device__ inline unsigned pk2(float lo, float hi) {
    union { __hip_bfloat162 h; unsigned u; } cv;
    cv.h = __float22bfloat162_rn(make_float2(lo, hi));
    return cv.u;
}
static __device__ inline short8 mk8(unsigned u0, unsigned u1, unsigned u2, unsigned u3) {
    union { short8 v; unsigned u[4]; } r;
    r.u[0] = u0; r.u[1] = u1; r.u[2] = u2; r.u[3] = u3;
    return r.v;
}
static __device__ inline short8 S8(uint4 u) {
    union { uint4 a; short8 v; } c; c.a = u; return c.v;
}
static __device__ inline void pl32swap(unsigned& x, unsigned& y) {
    asm("v_permlane32_swap_b32 %0, %1" : "+v"(x), "+v"(y));
}
static __device__ inline f32x16 MFMA(short8 a, short8 b, f32x16 c) {
    return __builtin_amdgcn_mfma_f32_32x32x16_bf16(a, b, c, 0, 0, 0);
}
static __device__ inline f32x16 zero16() {
    f32x16 z = {0.f,0.f,0.f,0.f,0.f,0.f,0.f,0.f,0.f,0.f,0.f,0.f,0.f,0.f,0.f,0.f};
    return z;
}

// ---------------- prestage: middle -> d_ws bf16 fragments ----------------
// ws uint4 index: ((site*2+s)*4 + k*2 + h)*64 + hi*32 + col
// word w4 of a frag = pk2(a[16h+8hi+2w4][col], a[16h+8hi+2w4+1][col]), a = mid[:,:,k]-I
__global__ __launch_bounds__(256) void mpdo_prestage(
    const float* __restrict__ middle, unsigned* __restrict__ ws)
{
    const int site = blockIdx.x;          // 0..61
    const int t    = threadIdx.x;
    const int s    = t >> 7;
    const int h    = (t >> 6) & 1;
    const int hi   = (t >> 5) & 1;
    const int col  = t & 31;
    const float2* m2 = (const float2*)middle + (size_t)(site*2 + s) * 1024;
    float2 v[8];
    #pragma unroll
    for (int e = 0; e < 8; ++e) {
        const int kk = 16*h + 8*hi + e;
        float2 d = m2[kk*32 + col];
        if (kk == col) { d.x -= 1.f; d.y -= 1.f; }
        v[e] = d;
    }
    uint4 o0, o1;
    o0.x = pk2(v[0].x, v[1].x); o0.y = pk2(v[2].x, v[3].x);
    o0.z = pk2(v[4].x, v[5].x); o0.w = pk2(v[6].x, v[7].x);
    o1.x = pk2(v[0].y, v[1].y); o1.y = pk2(v[2].y, v[3].y);
    o1.z = pk2(v[4].y, v[5].y); o1.w = pk2(v[6].y, v[7].y);
    uint4* w4 = (uint4*)ws;
    const int lane_off = hi*32 + col;
    w4[((site*2 + s)*4 + 0 + h)*64 + lane_off] = o0;   // k=0
    w4[((site*2 + s)*4 + 2 + h)*64 + lane_off] = o1;   // k=1
}

// ---------------- main: 1 wave / element, barrier-free ----------------
#define SITE_BODY(CA, CB, NA, NB, SITE)                                          \
  {                                                                              \
    /* EA source: transposed-E reads from per-wave LDS (written last site) */    \
    float ef[16];                                                                \
    _Pragma("unroll")                                                            \
    for (int h = 0; h < 2; ++h) {                                                \
      const int base = col*EPITCH + 16*h + 8*hi;                                 \
      _Pragma("unroll")                                                          \
      for (int c = 0; c < 8; ++c) ef[h*8 + c] = Ew[base + c];                    \
    }                                                                            \
    /* EB: B-op of E from e regs */                                              \
    short8 EB[2];                                                                \
    _Pragma("unroll")                                                            \
    for (int h = 0; h < 2; ++h) {                                                \
      unsigned ua = pk2(e[8*h+0], e[8*h+1]);                                     \
      unsigned ub = pk2(e[8*h+2], e[8*h+3]);                                     \
      unsigned uc = pk2(e[8*h+4], e[8*h+5]);                                     \
      unsigned ud = pk2(e[8*h+6], e[8*h+7]);                                     \
      pl32swap(ua, uc); pl32swap(ub, ud);                                        \
      EB[h] = mk8(ua, ub, uc, ud);                                               \
    }                                                                            \
    /* P_k = a_k^T E */                                                          \
    f32x16 acc0 = MFMA(S8(CA[0]), EB[0], zero16());                              \
    acc0 = MFMA(S8(CA[1]), EB[1], acc0);                                         \
    f32x16 acc1 = MFMA(S8(CA[2]), EB[0], zero16());                              \
    acc1 = MFMA(S8(CA[3]), EB[1], acc1);                                         \
    /* EA pack */                                                                \
    short8 EA[2];                                                                \
    _Pragma("unroll")                                                            \
    for (int h = 0; h < 2; ++h)                                                  \
      EA[h] = mk8(pk2(ef[8*h+0], ef[8*h+1]), pk2(ef[8*h+2], ef[8*h+3]),          \
                  pk2(ef[8*h+4], ef[8*h+5]), pk2(ef[8*h+6], ef[8*h+7]));         \
    /* V_k = E b_k */                                                            \
    f32x16 V0 = MFMA(EA[0], S8(CB[0]), zero16());                                \
    V0 = MFMA(EA[1], S8(CB[1]), V0);                                             \
    f32x16 V1 = MFMA(EA[0], S8(CB[2]), zero16());                                \
    V1 = MFMA(EA[1], S8(CB[3]), V1);                                             \
    /* prefetch next site's fragments (ping-pong regs) */                        \
    {                                                                            \
      const int pfi = ((SITE) < 62) ? (SITE) : 61;                               \
      const int ba = (pfi*2 + srn)*4, bb = (pfi*2 + scn)*4;                      \
      _Pragma("unroll")                                                          \
      for (int kh = 0; kh < 4; ++kh) {                                           \
        NA[kh] = w4g[(ba + kh)*64 + lane_off];                                   \
        NB[kh] = w4g[(bb + kh)*64 + lane_off];                                   \
      }                                                                          \
      const int qi = ((SITE) + 2 <= 62) ? (SITE) + 2 : 62;                       \
      srn = q[qi]; scn = q[qi + 64];                                             \
    }                                                                            \
    /* third term: acc_k += a_k^T V_k */                                         \
    _Pragma("unroll")                                                            \
    for (int h = 0; h < 2; ++h) {                                                \
      unsigned ua = pk2(V0[8*h+0], V0[8*h+1]);                                   \
      unsigned ub = pk2(V0[8*h+2], V0[8*h+3]);                                   \
      unsigned uc = pk2(V0[8*h+4], V0[8*h+5]);                                   \
      unsigned ud = pk2(V0[8*h+6], V0[8*h+7]);                                   \
      pl32swap(ua, uc); pl32swap(ub, ud);                                        \
      acc0 = MFMA(S8(CA[h]), mk8(ua, ub, uc, ud), acc0);                         \
    }                                                                            \
    _Pragma("unroll")                                                            \
    for (int h = 0; h < 2; ++h) {                                                \
      unsigned ua = pk2(V1[8*h+0], V1[8*h+1]);                                   \
      unsigned ub = pk2(V1[8*h+2], V1[8*h+3]);                                   \
      unsigned uc = pk2(V1[8*h+4], V1[8*h+5]);                                   \
      unsigned ud = pk2(V1[8*h+6], V1[8*h+7]);                                   \
      pl32swap(ua, uc); pl32swap(ub, ud);                                        \
      acc1 = MFMA(S8(CA[2+h]), mk8(ua, ub, uc, ud), acc1);                       \
    }                                                                            \
    /* E' = 2E + P0 + P1 + V0 + V1 ; stash transposed copy for next site */      \
    _Pragma("unroll")                                                            \
    for (int r = 0; r < 16; ++r)                                                 \
      e[r] = fmaf(2.f, e[r], (acc0[r] + acc1[r]) + (V0[r] + V1[r]));             \
    _Pragma("unroll")                                                            \
    for (int r = 0; r < 16; ++r) Ew[rowr[r]*EPITCH + col] = e[r];                \
  }

__global__ __launch_bounds__(256, 2) void mpdo_ws(
    const int*      __restrict__ qn,
    const float*    __restrict__ left,
    const float*    __restrict__ right,
    const unsigned* __restrict__ ws,
    float*          __restrict__ out,
    const int       cplx)
{
    __shared__ float E_all[4][32*EPITCH];      // per-wave transpose buffer, 16.9 KB

    const int t    = threadIdx.x;
    const int w    = t >> 6;
    const int lane = t & 63;
    const int hi   = lane >> 5;
    const int col  = lane & 31;
    const int elem = blockIdx.x * 4 + w;
    const int* q   = qn + (size_t)elem * 128;
    float* Ew = E_all[w];
    const int lane_off = hi*32 + col;
    const uint4* w4g = (const uint4*)ws;

    int rowr[16];
    #pragma unroll
    for (int r = 0; r < 16; ++r) rowr[r] = (r & 3) + 8*(r >> 2) + 4*hi;

    // init edge (fp32 C-layout regs) + seed transpose buffer
    float e[16];
    {
        const float* Lr = left + (size_t)q[0]  * 64;
        const float* Lc = left + (size_t)q[64] * 64;
        const float c0v = Lc[col*2 + 0], c1v = Lc[col*2 + 1];
        #pragma unroll
        for (int r = 0; r < 16; ++r)
            e[r] = Lr[rowr[r]*2 + 0] * c0v + Lr[rowr[r]*2 + 1] * c1v;
    }
    #pragma unroll
    for (int r = 0; r < 16; ++r) Ew[rowr[r]*EPITCH + col] = e[r];

    // prologue: fragments for site 1
    uint4 CA[4], CB[4], NA[4], NB[4];
    {
        const int sr = q[1], sc = q[65];
        const int ba = sr*4, bb = sc*4;      // site index 0
        #pragma unroll
        for (int kh = 0; kh < 4; ++kh) {
            CA[kh] = w4g[(ba + kh)*64 + lane_off];
            CB[kh] = w4g[(bb + kh)*64 + lane_off];
        }
    }
    int srn = q[2], scn = q[66];

    #pragma unroll 1
    for (int it = 0; it < 31; ++it) {
        const int siteA = 2*it + 1;
        SITE_BODY(CA, CB, NA, NB, siteA)
        SITE_BODY(NA, NB, CA, CB, siteA + 1)
    }

    // epilogue
    {
        const float* Rr = right + (size_t)q[63]  * 64;
        const float* Rc = right + (size_t)q[127] * 64;
        const float rc0 = Rc[col*2 + 0], rc1 = Rc[col*2 + 1];
        float part = 0.f;
        #pragma unroll
        for (int r = 0; r < 16; ++r) {
            const float re = Rr[rowr[r]*2 + 0]*rc0 + Rr[rowr[r]*2 + 1]*rc1;
            part += e[r] * re;
        }
        #pragma unroll
        for (int off = 32; off > 0; off >>= 1)
            part += __shfl_down(part, off, 64);
        if (lane == 0) {
            const float re = logf(fabsf(part));
            if (cplx) {
                out[2*elem + 0] = re;
                out[2*elem + 1] = (part < 0.f) ? 3.14159265358979323846f : 0.f;
            } else {
                out[elem] = re;
            }
        }
    }
}

// ---------------- fallback: r9 kernel (proven, 99 us) if ws too small ----------------
__global__ __launch_bounds__(256, 2) void mpdo_mfma_fb(
    const int* __restrict__ qn, const float* __restrict__ left,
    const float* __restrict__ right, const float* __restrict__ middle,
    float* __restrict__ out, const int cplx)
{
    __shared__ unsigned mid_b[2048];
    __shared__ float    E_s[4][32*EPITCH];

    const int t = threadIdx.x, w = t >> 6, lane = t & 63;
    const int hi = lane >> 5, col = lane & 31;
    const int elem = blockIdx.x * 4 + w;
    const int* q = qn + (size_t)elem * 128;
    float* Ew = E_s[w];
    const int sp = (t >> 4) & 15, sj = t & 15, jj = sj * 2;
    const float dj = (sp == sj) ? 1.0f : 0.0f;
    const int v0 = (0 + 2*sp) * 16 + sj, v1 = (32 + 2*sp) * 16 + sj;

    int rowr[16];
    #pragma unroll
    for (int r = 0; r < 16; ++r) rowr[r] = (r & 3) + 8*(r >> 2) + 4*hi;

    float e[16];
    {
        const float* Lr = left + (size_t)q[0]  * 64;
        const float* Lc = left + (size_t)q[64] * 64;
        const float c0v = Lc[col*2 + 0], c1v = Lc[col*2 + 1];
        #pragma unroll
        for (int r = 0; r < 16; ++r)
            e[r] = Lr[rowr[r]*2 + 0] * c0v + Lr[rowr[r]*2 + 1] * c1v;
    }
    const float4* gm = (const float4*)middle;
    float4 A0 = gm[v0], A1 = gm[v0 + 16], B0 = gm[v1], B1 = gm[v1 + 16];
    int srn = q[1], scn = q[65];

    for (int site = 1; site <= 62; ++site) {
        {
            uint2* m2 = (uint2*)mid_b;
            m2[((0*16 + sp)*32 + jj) >> 1] = make_uint2(pk2(A0.x - dj, A1.x), pk2(A0.z, A1.z - dj));
            m2[((1*16 + sp)*32 + jj) >> 1] = make_uint2(pk2(A0.y - dj, A1.y), pk2(A0.w, A1.w - dj));
            m2[((2*16 + sp)*32 + jj) >> 1] = make_uint2(pk2(B0.x - dj, B1.x), pk2(B0.z, B1.z - dj));
            m2[((3*16 + sp)*32 + jj) >> 1] = make_uint2(pk2(B0.y - dj, B1.y), pk2(B0.w, B1.w - dj));
        }
        #pragma unroll
        for (int r = 0; r < 16; ++r) Ew[rowr[r]*EPITCH + col] = e[r];
        __syncthreads();
        const int sr = srn, sc = scn;
        if (site < 62) {
            const float4* gn = (const float4*)(middle + (size_t)site * 4096);
            A0 = gn[v0]; A1 = gn[v0 + 16]; B0 = gn[v1]; B1 = gn[v1 + 16];
            srn = q[site + 1]; scn = q[site + 65];
        }
        short8 aT[2][2], bF[2][2];
        #pragma unroll
        for (int k = 0; k < 2; ++k)
            #pragma unroll
            for (int h = 0; h < 2; ++h) {
                const int pa = ((sr*2 + k)*16 + 8*h + 4*hi) * 32 + col;
                aT[k][h] = mk8(mid_b[pa], mid_b[pa+32], mid_b[pa+64], mid_b[pa+96]);
                const int pb = ((sc*2 + k)*16 + 8*h + 4*hi) * 32 + col;
                bF[k][h] = mk8(mid_b[pb], mid_b[pb+32], mid_b[pb+64], mid_b[pb+96]);
            }
        short8 EA[2];
        #pragma unroll
        for (int h = 0; h < 2; ++h) {
            const int base = col*EPITCH + 16*h + 8*hi;
            EA[h] = mk8(pk2(Ew[base+0], Ew[base+1]), pk2(Ew[base+2], Ew[base+3]),
                        pk2(Ew[base+4], Ew[base+5]), pk2(Ew[base+6], Ew[base+7]));
        }
        short8 EB[2];
        #pragma unroll
        for (int h = 0; h < 2; ++h) {
            unsigned ua = pk2(e[8*h+0], e[8*h+1]);
            unsigned ub = pk2(e[8*h+2], e[8*h+3]);
            unsigned uc = pk2(e[8*h+4], e[8*h+5]);
            unsigned ud = pk2(e[8*h+6], e[8*h+7]);
            pl32swap(ua, uc); pl32swap(ub, ud);
            EB[h] = mk8(ua, ub, uc, ud);
        }
        f32x16 V0 = MFMA(EA[0], bF[0][0], zero16()); V0 = MFMA(EA[1], bF[0][1], V0);
        f32x16 V1 = MFMA(EA[0], bF[1][0], zero16()); V1 = MFMA(EA[1], bF[1][1], V1);
        f32x16 acc = MFMA(aT[0][0], EB[0], zero16());
        acc = MFMA(aT[0][1], EB[1], acc);
        acc = MFMA(aT[1][0], EB[0], acc);
        acc = MFMA(aT[1][1], EB[1], acc);
        #pragma unroll
        for (int k = 0; k < 2; ++k) {
            const f32x16& V = k ? V1 : V0;
            #pragma unroll
            for (int h = 0; h < 2; ++h) {
                unsigned ua = pk2(V[8*h+0], V[8*h+1]);
                unsigned ub = pk2(V[8*h+2], V[8*h+3]);
                unsigned uc = pk2(V[8*h+4], V[8*h+5]);
                unsigned ud = pk2(V[8*h+6], V[8*h+7]);
                pl32swap(ua, uc); pl32swap(ub, ud);
                acc = MFMA(aT[k][h], mk8(ua, ub, uc, ud), acc);
            }
        }
        #pragma unroll
        for (int r = 0; r < 16; ++r)
            e[r] = 2.0f*e[r] + acc[r] + V0[r] + V1[r];
        __syncthreads();
    }
    {
        const float* Rr = right + (size_t)q[63]  * 64;
        const float* Rc = right + (size_t)q[127] * 64;
        const float rc0 = Rc[col*2 + 0], rc1 = Rc[col*2 + 1];
        float part = 0.f;
        #pragma unroll
        for (int r = 0; r < 16; ++r)
            part += e[r] * (Rr[rowr[r]*2 + 0]*rc0 + Rr[rowr[r]*2 + 1]*rc1);
        #pragma unroll
        for (int off = 32; off > 0; off >>= 1)
            part += __shfl_down(part, off, 64);
        if (lane == 0) {
            const float re = logf(fabsf(part));
            if (cplx) { out[2*elem] = re; out[2*elem+1] = (part < 0.f) ? 3.14159265f : 0.f; }
            else      { out[elem] = re; }
        }
    }
}

extern "C" void kernel_launch(void* const* d_in, const int* in_sizes, int n_in,
                              void* d_out, int out_size, void* d_ws, size_t ws_size,
                              hipStream_t stream) {
    const int*   qn     = (const int*)  d_in[0];
    const float* left   = (const float*)d_in[1];
    const float* right  = (const float*)d_in[2];
    const float* middle = (const float*)d_in[3];
    float* out = (float*)d_out;

    const int B    = in_sizes[0] / 128;
    const int cplx = (out_size >= 2 * B) ? 1 : 0;
    const size_t need = 62ull * 8192ull;      // 496 KB of bf16 fragments

    if (ws_size >= need) {
        mpdo_prestage<<<62, 256, 0, stream>>>(middle, (unsigned*)d_ws);
        mpdo_ws<<<B / 4, 256, 0, stream>>>(qn, left, right, (const unsigned*)d_ws,
                                           out, cplx);
    } else {
        mpdo_mfma_fb<<<B / 4, 256, 0, stream>>>(qn, left, right, middle, out, cplx);
    }
}